// Round 3
// baseline (263.109 us; speedup 1.0000x reference)
//
#include <hip/hip_runtime.h>

#define N_USERS 16384
#define N_MOVIES 8192
#define LATENT 5

constexpr int BLOCK = 256;
constexpr int TU = 64;                  // users per tile
constexpr int MPT = 8;                  // movies per thread (2x float4 per row)
constexpr int TM = BLOCK * MPT;         // 2048 movies per tile
constexpr int MTILES = N_MOVIES / TM;   // 4
constexpr int UTILES = N_USERS / TU;    // 256
constexpr int NBLOCKS = UTILES * MTILES;            // 1024
constexpr int NORM_ROWS = N_USERS + N_MOVIES;       // 24576
constexpr int NORM_PER_BLOCK = NORM_ROWS / NBLOCKS; // 24
constexpr int DEPTH = 4;                // rows in the register slot ring

__device__ inline float wave_reduce(float v) {
    #pragma unroll
    for (int off = 32; off > 0; off >>= 1)
        v += __shfl_down(v, off, 64);
    return v;
}

__global__ __launch_bounds__(BLOCK, 4) void pmf_kernel(
        const float* __restrict__ M, const float* __restrict__ U,
        const float* __restrict__ V, float* __restrict__ out) {
    __shared__ float uS[TU][LATENT];    // 1.28 KB user features for this tile
    __shared__ float red[BLOCK / 64];

    const int tid = (int)threadIdx.x;
    const int mtile = (int)blockIdx.x % MTILES;
    const int utile = (int)blockIdx.x / MTILES;
    const int u0 = utile * TU;
    const int m0 = mtile * TM + tid * MPT;

    for (int i = tid; i < TU * LATENT; i += BLOCK)
        uS[i / LATENT][i % LATENT] = U[(size_t)u0 * LATENT + i];
    __syncthreads();

    // This thread's 8 movies' V-features: 40 consecutive floats, 16B-aligned.
    float vbuf[MPT * LATENT];
    {
        const float4* vp = reinterpret_cast<const float4*>(&V[(size_t)m0 * LATENT]);
        #pragma unroll
        for (int i = 0; i < MPT * LATENT / 4; ++i)
            reinterpret_cast<float4*>(vbuf)[i] = vp[i];
    }

    // Fused regularization: this block's 24-row slice of the U/V norm sums.
    float acc0 = 0.f, acc1 = 0.f;
    {
        const int idx = (int)blockIdx.x * NORM_PER_BLOCK + tid;
        if (tid < NORM_PER_BLOCK) {
            const float* f = (idx < N_USERS)
                                 ? &U[(size_t)idx * LATENT]
                                 : &V[(size_t)(idx - N_USERS) * LATENT];
            float s = 0.f;
            #pragma unroll
            for (int k = 0; k < LATENT; ++k) s = fmaf(f[k], f[k], s);
            acc0 = 0.3f * sqrtf(s);
        }
    }

    // Depth-4 rolling register pipeline over the 64 user rows: while row r is
    // computed, rows r+1..r+3 are in flight (6 KB/wave outstanding).
    const float* base = &M[(size_t)u0 * N_MOVIES + m0];
    float4 pa[DEPTH], pb[DEPTH];
    #pragma unroll
    for (int i = 0; i < DEPTH; ++i) {
        const float* rp = base + (size_t)i * N_MOVIES;
        pa[i] = *reinterpret_cast<const float4*>(rp);
        pb[i] = *reinterpret_cast<const float4*>(rp + 4);
    }

    for (int uu = 0; uu < TU; uu += DEPTH) {
        #pragma unroll
        for (int i = 0; i < DEPTH; ++i) {   // all slot indices compile-time
            const int r = uu + i;
            float uc[LATENT];
            #pragma unroll
            for (int k = 0; k < LATENT; ++k) uc[k] = uS[r][k];

            const float4 x0 = pa[i], x1 = pb[i];

            // Refill slot i with row r+DEPTH (clamped tail reads hit L1).
            const int nr = (r + DEPTH < TU) ? (r + DEPTH) : (TU - 1);
            const float* rp = base + (size_t)nr * N_MOVIES;
            pa[i] = *reinterpret_cast<const float4*>(rp);
            pb[i] = *reinterpret_cast<const float4*>(rp + 4);

            const float mv[MPT] = {x0.x, x0.y, x0.z, x0.w, x1.x, x1.y, x1.z, x1.w};
            #pragma unroll
            for (int j = 0; j < MPT; ++j) {
                float s = uc[0] * vbuf[j * LATENT + 0];
                s = fmaf(uc[1], vbuf[j * LATENT + 1], s);
                s = fmaf(uc[2], vbuf[j * LATENT + 2], s);
                s = fmaf(uc[3], vbuf[j * LATENT + 3], s);
                s = fmaf(uc[4], vbuf[j * LATENT + 4], s);
                float t = __expf(-s);                       // v_exp_f32 path
                float p = __builtin_amdgcn_rcpf(1.0f + t);  // fast rcp
                float e = (mv[j] != -1.0f) ? (mv[j] - p) : 0.0f;
                if (j & 1) acc1 = fmaf(e, e, acc1);
                else       acc0 = fmaf(e, e, acc0);
            }
        }
    }

    // Block-level reduction -> single atomic per block.
    float tot = wave_reduce(acc0 + acc1);
    if ((tid & 63) == 0) red[tid >> 6] = tot;
    __syncthreads();
    if (tid == 0)
        atomicAdd(out, red[0] + red[1] + red[2] + red[3]);
}

extern "C" void kernel_launch(void* const* d_in, const int* in_sizes, int n_in,
                              void* d_out, int out_size, void* d_ws, size_t ws_size,
                              hipStream_t stream) {
    const float* M = (const float*)d_in[0];   // matrix        [16384, 8192]
    const float* U = (const float*)d_in[1];   // user_features [16384, 5]
    const float* V = (const float*)d_in[2];   // movie_features [8192, 5]
    float* out = (float*)d_out;

    // d_out is poisoned once and never re-poisoned between replays: zero it
    // every call (async memset is graph-capture-safe).
    hipMemsetAsync(out, 0, sizeof(float), stream);

    pmf_kernel<<<NBLOCKS, BLOCK, 0, stream>>>(M, U, V, out);
}

// Round 4
// 146.173 us; speedup vs baseline: 1.8000x; 1.8000x over previous
//
#include <hip/hip_runtime.h>

#define N_USERS 16384
#define N_MOVIES 8192
#define LATENT 5

constexpr int BLOCK = 256;
constexpr int TU = 64;                  // users per tile
constexpr int MPT = 4;                  // movies per thread (one float4 per row)
constexpr int TM = BLOCK * MPT;         // 1024 movies per tile
constexpr int MTILES = N_MOVIES / TM;   // 8
constexpr int UTILES = N_USERS / TU;    // 256
constexpr int NBLOCKS = UTILES * MTILES;            // 2048
constexpr int NORM_ROWS = N_USERS + N_MOVIES;       // 24576
constexpr int NORM_PER_BLOCK = NORM_ROWS / NBLOCKS; // 12
constexpr int DEPTH = 8;                // rows in the register slot ring

__device__ inline float wave_reduce(float v) {
    #pragma unroll
    for (int off = 32; off > 0; off >>= 1)
        v += __shfl_down(v, off, 64);
    return v;
}

__global__ __launch_bounds__(BLOCK, 4) void pmf_kernel(
        const float* __restrict__ M, const float* __restrict__ U,
        const float* __restrict__ V, float* __restrict__ out) {
    __shared__ float uS[TU][LATENT];    // 1.28 KB user features for this tile
    __shared__ float red[BLOCK / 64];

    const int tid = (int)threadIdx.x;
    const int mtile = (int)blockIdx.x % MTILES;
    const int utile = (int)blockIdx.x / MTILES;
    const int u0 = utile * TU;
    const int m0 = mtile * TM + tid * MPT;

    for (int i = tid; i < TU * LATENT; i += BLOCK)
        uS[i / LATENT][i % LATENT] = U[(size_t)u0 * LATENT + i];
    __syncthreads();

    // This thread's 4 movies' V-features: 20 consecutive floats, 16B-aligned
    // (m0 multiple of 4 -> byte offset m0*20 multiple of 80... use float4x5).
    float vbuf[MPT * LATENT];
    {
        const float4* vp = reinterpret_cast<const float4*>(&V[(size_t)m0 * LATENT]);
        #pragma unroll
        for (int i = 0; i < MPT * LATENT / 4; ++i)
            reinterpret_cast<float4*>(vbuf)[i] = vp[i];
    }

    // Fused regularization: this block's 12-row slice of the U/V norm sums.
    float acc0 = 0.f, acc1 = 0.f;
    {
        const int idx = (int)blockIdx.x * NORM_PER_BLOCK + tid;
        if (tid < NORM_PER_BLOCK) {
            const float* f = (idx < N_USERS)
                                 ? &U[(size_t)idx * LATENT]
                                 : &V[(size_t)(idx - N_USERS) * LATENT];
            float s = 0.f;
            #pragma unroll
            for (int k = 0; k < LATENT; ++k) s = fmaf(f[k], f[k], s);
            acc0 = 0.3f * sqrtf(s);
        }
    }

    // Depth-8 rolling register ring over the 64 user rows: while row r is
    // computed, rows r+1..r+7 are in flight (~7 KB/wave outstanding).
    // Total live VGPRs ~70 (ring 32 + vbuf 20 + misc) — no spill at cap 128.
    const float* base = &M[(size_t)u0 * N_MOVIES + m0];
    float4 p[DEPTH];
    #pragma unroll
    for (int i = 0; i < DEPTH; ++i)
        p[i] = *reinterpret_cast<const float4*>(base + (size_t)i * N_MOVIES);

    for (int uu = 0; uu < TU; uu += DEPTH) {
        #pragma unroll
        for (int i = 0; i < DEPTH; ++i) {   // all slot indices compile-time
            const int r = uu + i;
            float uc[LATENT];
            #pragma unroll
            for (int k = 0; k < LATENT; ++k) uc[k] = uS[r][k];

            const float4 x0 = p[i];

            // Refill slot i with row r+DEPTH (clamped tail reads hit L1).
            const int nr = (r + DEPTH < TU) ? (r + DEPTH) : (TU - 1);
            p[i] = *reinterpret_cast<const float4*>(base + (size_t)nr * N_MOVIES);

            const float mv[MPT] = {x0.x, x0.y, x0.z, x0.w};
            #pragma unroll
            for (int j = 0; j < MPT; ++j) {
                float s = uc[0] * vbuf[j * LATENT + 0];
                s = fmaf(uc[1], vbuf[j * LATENT + 1], s);
                s = fmaf(uc[2], vbuf[j * LATENT + 2], s);
                s = fmaf(uc[3], vbuf[j * LATENT + 3], s);
                s = fmaf(uc[4], vbuf[j * LATENT + 4], s);
                float t = __expf(-s);                       // v_exp_f32 path
                float p2 = __builtin_amdgcn_rcpf(1.0f + t); // fast rcp
                float e = (mv[j] != -1.0f) ? (mv[j] - p2) : 0.0f;
                if (j & 1) acc1 = fmaf(e, e, acc1);
                else       acc0 = fmaf(e, e, acc0);
            }
        }
    }

    // Block-level reduction -> single atomic per block.
    float tot = wave_reduce(acc0 + acc1);
    if ((tid & 63) == 0) red[tid >> 6] = tot;
    __syncthreads();
    if (tid == 0)
        atomicAdd(out, red[0] + red[1] + red[2] + red[3]);
}

extern "C" void kernel_launch(void* const* d_in, const int* in_sizes, int n_in,
                              void* d_out, int out_size, void* d_ws, size_t ws_size,
                              hipStream_t stream) {
    const float* M = (const float*)d_in[0];   // matrix        [16384, 8192]
    const float* U = (const float*)d_in[1];   // user_features [16384, 5]
    const float* V = (const float*)d_in[2];   // movie_features [8192, 5]
    float* out = (float*)d_out;

    // d_out is poisoned once and never re-poisoned between replays: zero it
    // every call (async memset is graph-capture-safe).
    hipMemsetAsync(out, 0, sizeof(float), stream);

    pmf_kernel<<<NBLOCKS, BLOCK, 0, stream>>>(M, U, V, out);
}

// Round 5
// 145.273 us; speedup vs baseline: 1.8111x; 1.0062x over previous
//
#include <hip/hip_runtime.h>

#define N_USERS 16384
#define N_MOVIES 8192
#define LATENT 5

constexpr int BLOCK = 256;
constexpr int TU = 64;                  // users per tile
constexpr int MPT = 4;                  // movies per thread (one float4 per row)
constexpr int TM = BLOCK * MPT;         // 1024 movies per tile
constexpr int MTILES = N_MOVIES / TM;   // 8
constexpr int UTILES = N_USERS / TU;    // 256
constexpr int NBLOCKS = UTILES * MTILES;            // 2048
constexpr int NORM_ROWS = N_USERS + N_MOVIES;       // 24576
constexpr int NORM_PER_BLOCK = NORM_ROWS / NBLOCKS; // 12
constexpr int DEPTH = 8;                // rows in the register slot ring

__device__ inline float wave_reduce(float v) {
    #pragma unroll
    for (int off = 32; off > 0; off >>= 1)
        v += __shfl_down(v, off, 64);
    return v;
}

__global__ __launch_bounds__(BLOCK, 4) void pmf_kernel(
        const float* __restrict__ M, const float* __restrict__ U,
        const float* __restrict__ V, float* __restrict__ out) {
    __shared__ float uS[TU][LATENT];    // 1.28 KB user features for this tile
    __shared__ float red[BLOCK / 64];

    const int tid = (int)threadIdx.x;

    // XCD-decorrelated tile mapping. Dispatch round-robins blockIdx across the
    // 8 XCDs (xcd ~= g % 8). The naive mtile = g % 8 makes mtile == XCD: each
    // XCD reads a fixed 4KB-of-32KB column comb -> channel-group congestion.
    // This bijection makes an XCD's resident blocks cycle all 8 column panels:
    //   mtile = (g/8) % 8, utile = (g%8)*32 + g/64.
    const int g = (int)blockIdx.x;
    const int mtile = (g >> 3) & (MTILES - 1);
    const int utile = (g & 7) * (UTILES / 8) + (g >> 6);
    const int u0 = utile * TU;
    const int m0 = mtile * TM + tid * MPT;

    for (int i = tid; i < TU * LATENT; i += BLOCK)
        uS[i / LATENT][i % LATENT] = U[(size_t)u0 * LATENT + i];
    __syncthreads();

    // This thread's 4 movies' V-features: 20 consecutive floats.
    float vbuf[MPT * LATENT];
    {
        const float4* vp = reinterpret_cast<const float4*>(&V[(size_t)m0 * LATENT]);
        #pragma unroll
        for (int i = 0; i < MPT * LATENT / 4; ++i)
            reinterpret_cast<float4*>(vbuf)[i] = vp[i];
    }

    // Fused regularization: this block's 12-row slice of the U/V norm sums
    // (uses raw blockIdx; any bijective slice assignment is fine).
    float acc0 = 0.f, acc1 = 0.f;
    {
        const int idx = g * NORM_PER_BLOCK + tid;
        if (tid < NORM_PER_BLOCK) {
            const float* f = (idx < N_USERS)
                                 ? &U[(size_t)idx * LATENT]
                                 : &V[(size_t)(idx - N_USERS) * LATENT];
            float s = 0.f;
            #pragma unroll
            for (int k = 0; k < LATENT; ++k) s = fmaf(f[k], f[k], s);
            acc0 = 0.3f * sqrtf(s);
        }
    }

    // Depth-8 rolling register ring over the 64 user rows (unchanged from R4).
    const float* base = &M[(size_t)u0 * N_MOVIES + m0];
    float4 p[DEPTH];
    #pragma unroll
    for (int i = 0; i < DEPTH; ++i)
        p[i] = *reinterpret_cast<const float4*>(base + (size_t)i * N_MOVIES);

    for (int uu = 0; uu < TU; uu += DEPTH) {
        #pragma unroll
        for (int i = 0; i < DEPTH; ++i) {   // all slot indices compile-time
            const int r = uu + i;
            float uc[LATENT];
            #pragma unroll
            for (int k = 0; k < LATENT; ++k) uc[k] = uS[r][k];

            const float4 x0 = p[i];

            // Refill slot i with row r+DEPTH (clamped tail reads hit L1).
            const int nr = (r + DEPTH < TU) ? (r + DEPTH) : (TU - 1);
            p[i] = *reinterpret_cast<const float4*>(base + (size_t)nr * N_MOVIES);

            const float mv[MPT] = {x0.x, x0.y, x0.z, x0.w};
            #pragma unroll
            for (int j = 0; j < MPT; ++j) {
                float s = uc[0] * vbuf[j * LATENT + 0];
                s = fmaf(uc[1], vbuf[j * LATENT + 1], s);
                s = fmaf(uc[2], vbuf[j * LATENT + 2], s);
                s = fmaf(uc[3], vbuf[j * LATENT + 3], s);
                s = fmaf(uc[4], vbuf[j * LATENT + 4], s);
                float t = __expf(-s);                       // v_exp_f32 path
                float p2 = __builtin_amdgcn_rcpf(1.0f + t); // fast rcp
                float e = (mv[j] != -1.0f) ? (mv[j] - p2) : 0.0f;
                if (j & 1) acc1 = fmaf(e, e, acc1);
                else       acc0 = fmaf(e, e, acc0);
            }
        }
    }

    // Block-level reduction -> single atomic per block.
    float tot = wave_reduce(acc0 + acc1);
    if ((tid & 63) == 0) red[tid >> 6] = tot;
    __syncthreads();
    if (tid == 0)
        atomicAdd(out, red[0] + red[1] + red[2] + red[3]);
}

extern "C" void kernel_launch(void* const* d_in, const int* in_sizes, int n_in,
                              void* d_out, int out_size, void* d_ws, size_t ws_size,
                              hipStream_t stream) {
    const float* M = (const float*)d_in[0];   // matrix        [16384, 8192]
    const float* U = (const float*)d_in[1];   // user_features [16384, 5]
    const float* V = (const float*)d_in[2];   // movie_features [8192, 5]
    float* out = (float*)d_out;

    // d_out is poisoned once and never re-poisoned between replays: zero it
    // every call (async memset is graph-capture-safe).
    hipMemsetAsync(out, 0, sizeof(float), stream);

    pmf_kernel<<<NBLOCKS, BLOCK, 0, stream>>>(M, U, V, out);
}